// Round 1
// baseline (5754.281 us; speedup 1.0000x reference)
//
#include <hip/hip_runtime.h>
#include <math.h>

// leaky_current_RNN: B=128, T=512, I=4, H=512, O=3, alpha=0.5, n_reg=256.
// Strategy: W_rec held in VGPRs across 4-block groups (512x128 f32 slice per
// block = 128 regs/thread); 64 groups x 2 batch rows; flag-barrier sync per
// step among the 4 members; hidden_states output doubles as the h
// communication buffer. Cooperative launch guarantees co-residency.

#define BB 128
#define TT 512
#define II 4
#define HH 512
#define OO 3
#define NREG_ 256

#define NTHREADS 512
#define MEMBERS 4      // blocks per group (column split of W_rec)
#define JSLICE 128     // columns per member
#define ROWS 2         // batch rows per group
#define KSPLIT 4       // k-chunks (split reduction)
#define KCH 128        // k per chunk
#define NGROUPS 64
#define NBLOCKS (NGROUPS * MEMBERS)
#define FLAG_STRIDE 32 // uint32 stride between group counters (128B)

__global__ __launch_bounds__(NTHREADS, 2)
void rnn_main(const float* __restrict__ x,
              const float* __restrict__ h0,
              const float* __restrict__ W_rec,
              const float* __restrict__ W_in,
              const float* __restrict__ bias_rec,
              const float* __restrict__ bias_in,
              float* __restrict__ hidden,          // (T+1, B, H) region of d_out
              unsigned int* __restrict__ flags,    // one counter per group
              float* __restrict__ partials)        // per-block reg partial
{
    const int tid  = threadIdx.x;
    const int bid  = blockIdx.x;
    // Group mapping: members of a group share bid%8 (same-XCD heuristic for
    // fast flag sync; correctness does not depend on it).
    const int xcd   = bid & 7;
    const int onx   = bid >> 3;          // 0..31 within XCD residue class
    const int memb  = onx & (MEMBERS - 1);
    const int group = xcd * 8 + (onx >> 2);   // 0..63
    const int r0    = group * ROWS;           // first global batch row
    const int j     = tid & (JSLICE - 1);
    const int ks    = tid >> 7;               // 0..3 k-chunk
    const int jglob = memb * JSLICE + j;

    __shared__ __align__(16) float a_s[ROWS][HH];        // tanh(h_prev)
    __shared__ float sc_s[KSPLIT][ROWS][JSLICE];         // split-k partials
    __shared__ float hprev_s[ROWS][JSLICE];              // raw h_prev, own cols
    __shared__ float xbuf[ROWS * TT * II];               // staged x rows
    __shared__ float win_s[II][JSLICE];                  // W_in slice
    __shared__ float ub_s[JSLICE];                       // bias_rec+bias_in
    __shared__ float red_s[NTHREADS / 64];

    // ---- one-time staging ----
    for (int idx = tid; idx < ROWS * TT * II; idx += NTHREADS) {
        int r   = idx >> 11;               // TT*II = 2048
        int rem = idx & (TT * II - 1);
        xbuf[idx] = x[(size_t)(r0 + r) * (TT * II) + rem];
    }
    if (tid < II * JSLICE) {
        int i = tid >> 7, jj = tid & (JSLICE - 1);
        win_s[i][jj] = W_in[i * HH + memb * JSLICE + jj];
    }
    if (tid < JSLICE) {
        ub_s[tid] = bias_rec[memb * JSLICE + tid] + bias_in[memb * JSLICE + tid];
    }

    // W_rec slice into registers: w[kk] = W_rec[ks*128+kk][jglob]
    float w[KCH];
#pragma unroll
    for (int kk = 0; kk < KCH; ++kk)
        w[kk] = W_rec[(size_t)(ks * KCH + kk) * HH + jglob];

    // hidden[0] = h0 (production 0)
    if (tid < ROWS * JSLICE) {
        int r = tid >> 7, jj = tid & (JSLICE - 1);
        hidden[(size_t)(r0 + r) * HH + memb * JSLICE + jj] =
            h0[(size_t)(r0 + r) * HH + memb * JSLICE + jj];
    }
    __syncthreads();   // drains vmcnt for all waves before the release below
    unsigned int* ctr = flags + group * FLAG_STRIDE;
    if (tid == 0) {
        __threadfence();
        __hip_atomic_fetch_add(ctr, 1u, __ATOMIC_RELEASE, __HIP_MEMORY_SCOPE_AGENT);
    }

    float racc  = 0.0f;
    float zprev = 0.0f;

    for (int t = 0; t < TT; ++t) {
        // wait for production t (hidden[t] complete from all 4 members)
        if (tid == 0) {
            const unsigned int target = (unsigned int)(MEMBERS * (t + 1));
            while (__hip_atomic_load(ctr, __ATOMIC_RELAXED, __HIP_MEMORY_SCOPE_AGENT) < target)
                __builtin_amdgcn_s_sleep(1);
            __threadfence();   // acquire: invalidate stale cache lines
        }
        __syncthreads();

        // a-phase: tanh(h_prev) -> LDS; stash raw own-slice h_prev
        const float* hp = hidden + (size_t)t * BB * HH + (size_t)r0 * HH;
        for (int idx = tid; idx < ROWS * HH; idx += NTHREADS) {
            int r = idx >> 9, k = idx & (HH - 1);
            float v = hp[idx];
            a_s[r][k] = tanhf(v);
            if ((k >> 7) == memb) hprev_s[r][k & (JSLICE - 1)] = v;
        }
        __syncthreads();

        // matvec against register-resident W slice
        float acc0 = 0.0f, acc1 = 0.0f;
        const float* ap0 = &a_s[0][ks * KCH];
        const float* ap1 = &a_s[1][ks * KCH];
#pragma unroll
        for (int q = 0; q < KCH / 4; ++q) {
            float4 a0 = *(const float4*)(ap0 + 4 * q);   // wave-uniform: LDS broadcast
            float4 a1 = *(const float4*)(ap1 + 4 * q);
            acc0 = fmaf(a0.x, w[4 * q + 0], acc0);
            acc0 = fmaf(a0.y, w[4 * q + 1], acc0);
            acc0 = fmaf(a0.z, w[4 * q + 2], acc0);
            acc0 = fmaf(a0.w, w[4 * q + 3], acc0);
            acc1 = fmaf(a1.x, w[4 * q + 0], acc1);
            acc1 = fmaf(a1.y, w[4 * q + 1], acc1);
            acc1 = fmaf(a1.z, w[4 * q + 2], acc1);
            acc1 = fmaf(a1.w, w[4 * q + 3], acc1);
        }
        sc_s[ks][0][j] = acc0;
        sc_s[ks][1][j] = acc1;
        __syncthreads();

        // finalize: z, h_new, store, reg accumulation
        if (tid < ROWS * JSLICE) {
            int r = tid >> 7;
            float z = ((sc_s[0][r][j] + sc_s[1][r][j]) +
                       (sc_s[2][r][j] + sc_s[3][r][j])) + ub_s[j];
            const float* xr = &xbuf[r * (TT * II) + t * II];
            z = fmaf(xr[0], win_s[0][j], z);
            z = fmaf(xr[1], win_s[1][j], z);
            z = fmaf(xr[2], win_s[2][j], z);
            z = fmaf(xr[3], win_s[3][j], z);
            float hpv = hprev_s[r][j];
            float hn  = 0.5f * hpv + 0.5f * z;
            hidden[(size_t)(t + 1) * BB * HH + (size_t)(r0 + r) * HH + jglob] = hn;
            if (jglob < NREG_) {
                float d1 = hn - hpv;
                racc = fmaf(d1, d1, racc);
                if (t > 0) { float d2 = z - zprev; racc = fmaf(d2, d2, racc); }
                zprev = z;
            }
        }
        __syncthreads();   // drain stores (all waves) before release
        if (tid == 0) {
            __threadfence();
            __hip_atomic_fetch_add(ctr, 1u, __ATOMIC_RELEASE, __HIP_MEMORY_SCOPE_AGENT);
        }
    }

    // block-reduce reg partial
    for (int off = 32; off; off >>= 1) racc += __shfl_down(racc, off);
    if ((tid & 63) == 0) red_s[tid >> 6] = racc;
    __syncthreads();
    if (tid == 0) {
        float s = 0.0f;
        for (int i = 0; i < NTHREADS / 64; ++i) s += red_s[i];
        partials[bid] = s;
    }
}

// outputs[b][t][:] = hidden[t+1][b][:] @ W_out   (one wave per (b,t))
__global__ __launch_bounds__(256)
void rnn_out(const float* __restrict__ hidden,
             const float* __restrict__ W_out,
             float* __restrict__ outputs)
{
    __shared__ float wout_s[HH * OO];
    const int tid = threadIdx.x;
    for (int i = tid; i < HH * OO; i += 256) wout_s[i] = W_out[i];
    __syncthreads();

    const int gid  = blockIdx.x * 4 + (tid >> 6);   // 0..65535
    const int lane = tid & 63;
    const int b = gid >> 9;
    const int t = gid & (TT - 1);
    const float* hp = hidden + (size_t)(t + 1) * BB * HH + (size_t)b * HH;

    float o0 = 0.0f, o1 = 0.0f, o2 = 0.0f;
#pragma unroll
    for (int q = 0; q < 8; ++q) {
        int k = lane + 64 * q;
        float hv = hp[k];
        o0 = fmaf(hv, wout_s[k * 3 + 0], o0);
        o1 = fmaf(hv, wout_s[k * 3 + 1], o1);
        o2 = fmaf(hv, wout_s[k * 3 + 2], o2);
    }
    for (int off = 32; off; off >>= 1) {
        o0 += __shfl_down(o0, off);
        o1 += __shfl_down(o1, off);
        o2 += __shfl_down(o2, off);
    }
    if (lane == 0) {
        float* op = outputs + (size_t)(b * TT + t) * OO;
        op[0] = o0; op[1] = o1; op[2] = o2;
    }
}

__global__ __launch_bounds__(256)
void rnn_tcr(const float* __restrict__ partials, float* __restrict__ tcr)
{
    __shared__ float red[4];
    const int tid = threadIdx.x;
    float v = partials[tid];   // NBLOCKS == 256 == blockDim
    for (int off = 32; off; off >>= 1) v += __shfl_down(v, off);
    if ((tid & 63) == 0) red[tid >> 6] = v;
    __syncthreads();
    if (tid == 0) {
        float s = red[0] + red[1] + red[2] + red[3];
        *tcr = s * (1.0f / ((float)TT * (float)BB * (float)NREG_));
    }
}

extern "C" void kernel_launch(void* const* d_in, const int* in_sizes, int n_in,
                              void* d_out, int out_size, void* d_ws, size_t ws_size,
                              hipStream_t stream)
{
    (void)in_sizes; (void)n_in; (void)out_size; (void)ws_size;

    const float* x     = (const float*)d_in[0];
    const float* h0    = (const float*)d_in[1];
    const float* W_rec = (const float*)d_in[2];
    const float* W_in  = (const float*)d_in[3];
    const float* W_out = (const float*)d_in[4];
    const float* brec  = (const float*)d_in[5];
    const float* bin   = (const float*)d_in[6];

    float* out     = (float*)d_out;
    float* outputs = out;                                   // (B,T,O)
    float* hidden  = out + (size_t)BB * TT * OO;            // (T+1,B,H)
    float* tcr     = out + (size_t)BB * TT * OO + (size_t)(TT + 1) * BB * HH;

    unsigned int* flags = (unsigned int*)d_ws;
    float* partials = (float*)((char*)d_ws + (size_t)NGROUPS * FLAG_STRIDE * 4);

    // zero the group counters every call (graph replays reuse d_ws)
    (void)hipMemsetAsync(d_ws, 0, (size_t)NGROUPS * FLAG_STRIDE * 4, stream);

    void* args[] = { (void*)&x, (void*)&h0, (void*)&W_rec, (void*)&W_in,
                     (void*)&brec, (void*)&bin, (void*)&hidden,
                     (void*)&flags, (void*)&partials };
    (void)hipLaunchCooperativeKernel((const void*)rnn_main,
                                     dim3(NBLOCKS), dim3(NTHREADS),
                                     args, 0, stream);

    rnn_out<<<dim3((BB * TT) / 4), dim3(256), 0, stream>>>(hidden, W_out, outputs);
    rnn_tcr<<<dim3(1), dim3(256), 0, stream>>>(partials, tcr);
}

// Round 2
// 1992.657 us; speedup vs baseline: 2.8877x; 2.8877x over previous
//
#include <hip/hip_runtime.h>
#include <math.h>

// leaky_current_RNN: B=128, T=512, I=4, H=512, O=3, alpha=0.5, n_reg=256.
// R2: (1) W_rec slice held in REAL VGPRs via static_for (compile-time indices
// -> SROA); (2) no threadfence anywhere -- h exchanged via relaxed agent-scope
// atomic (coherent/bypass) loads+stores, ordering via inline-asm vmcnt(0)
// before the group-counter fetch_add; (3) wave-granular release (4 finalize
// waves each +1, spin target 16*(t+1)).

#define BB 128
#define TT 512
#define II 4
#define HH 512
#define OO 3
#define NREG_ 256

#define NTHREADS 512
#define MEMBERS 4      // blocks per group (column split of W_rec)
#define JSLICE 128     // columns per member
#define ROWS 2         // batch rows per group
#define KSPLIT 4       // k-chunks (split reduction)
#define KCH 128        // k per chunk
#define NGROUPS 64
#define NBLOCKS (NGROUPS * MEMBERS)
#define FLAG_STRIDE 32 // uint32 stride between group counters (128B)

template <int I> struct IC { static constexpr int value = I; };
template <int N, int I = 0, typename F>
__device__ __forceinline__ void static_for(F&& f) {
    if constexpr (I < N) { f(IC<I>{}); static_for<N, I + 1>(f); }
}

__device__ __forceinline__ float coh_load(const float* p) {
    return __hip_atomic_load((const float*)p, __ATOMIC_RELAXED, __HIP_MEMORY_SCOPE_AGENT);
}
__device__ __forceinline__ void coh_store(float* p, float v) {
    __hip_atomic_store(p, v, __ATOMIC_RELAXED, __HIP_MEMORY_SCOPE_AGENT);
}

__global__ __launch_bounds__(NTHREADS, 2)
void rnn_main(const float* __restrict__ x,
              const float* __restrict__ h0,
              const float* __restrict__ W_rec,
              const float* __restrict__ W_in,
              const float* __restrict__ bias_rec,
              const float* __restrict__ bias_in,
              float* __restrict__ hidden,          // (T+1, B, H) region of d_out
              unsigned int* __restrict__ flags,    // one counter per group
              float* __restrict__ partials)        // per-block reg partial
{
    const int tid  = threadIdx.x;
    const int bid  = blockIdx.x;
    // Group mapping: members of a group share bid%8 (same-XCD heuristic for
    // fast flag sync; correctness does not depend on it).
    const int xcd   = bid & 7;
    const int onx   = bid >> 3;          // 0..31 within XCD residue class
    const int memb  = onx & (MEMBERS - 1);
    const int group = xcd * 8 + (onx >> 2);   // 0..63
    const int r0    = group * ROWS;           // first global batch row
    const int j     = tid & (JSLICE - 1);
    const int ks    = tid >> 7;               // 0..3 k-chunk
    const int jglob = memb * JSLICE + j;

    __shared__ __align__(16) float a_s[ROWS][HH];        // tanh(h_prev)
    __shared__ float sc_s[KSPLIT][ROWS][JSLICE];         // split-k partials
    __shared__ float hprev_s[2][ROWS][JSLICE];           // raw h_prev (dbuf)
    __shared__ float xbuf[ROWS * TT * II];               // staged x rows
    __shared__ float win_s[II][JSLICE];                  // W_in slice
    __shared__ float ub_s[JSLICE];                       // bias_rec+bias_in
    __shared__ float red_s[NTHREADS / 64];

    // ---- one-time staging (normal cached loads; nothing ever invalidates) --
    for (int idx = tid; idx < ROWS * TT * II; idx += NTHREADS) {
        int r   = idx >> 11;               // TT*II = 2048
        int rem = idx & (TT * II - 1);
        xbuf[idx] = x[(size_t)(r0 + r) * (TT * II) + rem];
    }
    if (tid < II * JSLICE) {
        int i = tid >> 7, jj = tid & (JSLICE - 1);
        win_s[i][jj] = W_in[i * HH + memb * JSLICE + jj];
    }
    if (tid < JSLICE) {
        ub_s[tid] = bias_rec[memb * JSLICE + tid] + bias_in[memb * JSLICE + tid];
    }

    // W_rec slice into registers: w[kk] = W_rec[ks*128+kk][jglob].
    // static_for => every index compile-time constant => stays in VGPRs.
    const float* wbase = W_rec + (size_t)(ks * KCH) * HH + jglob;
    float w[KCH];
    static_for<KCH>([&](auto kk) {
        w[kk.value] = wbase[(size_t)kk.value * HH];
    });

    unsigned int* ctr = flags + group * FLAG_STRIDE;

    // hidden[0] = h0 (production 0): coherent stores + wave-granular release
    if (tid < ROWS * JSLICE) {
        int r = tid >> 7;
        coh_store(&hidden[(size_t)(r0 + r) * HH + jglob],
                  h0[(size_t)(r0 + r) * HH + jglob]);
        asm volatile("s_waitcnt vmcnt(0)" ::: "memory");
        if ((tid & 63) == 0)
            __hip_atomic_fetch_add(ctr, 1u, __ATOMIC_RELAXED, __HIP_MEMORY_SCOPE_AGENT);
    }

    float racc  = 0.0f;
    float zprev = 0.0f;

    for (int t = 0; t < TT; ++t) {
        // wait for production t: 16*(t+1) wave-releases (4 waves x 4 members)
        {
            const unsigned int target = (unsigned int)(4 * MEMBERS * (t + 1));
            while (__hip_atomic_load(ctr, __ATOMIC_RELAXED, __HIP_MEMORY_SCOPE_AGENT) < target)
                __builtin_amdgcn_s_sleep(1);
            asm volatile("" ::: "memory");
        }

        // a-phase: coherent-load h_prev (LLC), tanh -> LDS; stash raw slice
        const float* hp = hidden + (size_t)t * BB * HH + (size_t)r0 * HH;
        {
            int k = tid;                       // 0..511
            float v0 = coh_load(hp + k);
            float v1 = coh_load(hp + HH + k);
            a_s[0][k] = tanhf(v0);
            a_s[1][k] = tanhf(v1);
            if ((k >> 7) == memb) {
                hprev_s[t & 1][0][k & (JSLICE - 1)] = v0;
                hprev_s[t & 1][1][k & (JSLICE - 1)] = v1;
            }
        }
        __syncthreads();

        // matvec against register-resident W slice (even/odd acc pairs)
        float acc0x = 0.0f, acc0y = 0.0f, acc1x = 0.0f, acc1y = 0.0f;
        const float* ap0 = &a_s[0][ks * KCH];
        const float* ap1 = &a_s[1][ks * KCH];
        static_for<KCH / 4>([&](auto qc) {
            constexpr int q = qc.value;
            float4 a0 = *(const float4*)(ap0 + 4 * q);   // wave-uniform: broadcast
            float4 a1 = *(const float4*)(ap1 + 4 * q);
            acc0x = fmaf(a0.x, w[4 * q + 0], acc0x);
            acc0y = fmaf(a0.y, w[4 * q + 1], acc0y);
            acc0x = fmaf(a0.z, w[4 * q + 2], acc0x);
            acc0y = fmaf(a0.w, w[4 * q + 3], acc0y);
            acc1x = fmaf(a1.x, w[4 * q + 0], acc1x);
            acc1y = fmaf(a1.y, w[4 * q + 1], acc1y);
            acc1x = fmaf(a1.z, w[4 * q + 2], acc1x);
            acc1y = fmaf(a1.w, w[4 * q + 3], acc1y);
        });
        sc_s[ks][0][j] = acc0x + acc0y;
        sc_s[ks][1][j] = acc1x + acc1y;
        __syncthreads();

        // finalize (waves 0-3): z, h_new, coherent store, wave release
        if (tid < ROWS * JSLICE) {
            int r = tid >> 7;
            float z = ((sc_s[0][r][j] + sc_s[1][r][j]) +
                       (sc_s[2][r][j] + sc_s[3][r][j])) + ub_s[j];
            const float* xr = &xbuf[r * (TT * II) + t * II];
            z = fmaf(xr[0], win_s[0][j], z);
            z = fmaf(xr[1], win_s[1][j], z);
            z = fmaf(xr[2], win_s[2][j], z);
            z = fmaf(xr[3], win_s[3][j], z);
            float hpv = hprev_s[t & 1][r][j];
            float hn  = 0.5f * hpv + 0.5f * z;
            coh_store(&hidden[(size_t)(t + 1) * BB * HH + (size_t)(r0 + r) * HH + jglob], hn);
            if (jglob < NREG_) {
                float d1 = hn - hpv;
                racc = fmaf(d1, d1, racc);
                if (t > 0) { float d2 = z - zprev; racc = fmaf(d2, d2, racc); }
                zprev = z;
            }
            // wave-granular release: all 64 lanes' stores drained, then +1
            asm volatile("s_waitcnt vmcnt(0)" ::: "memory");
            if ((tid & 63) == 0)
                __hip_atomic_fetch_add(ctr, 1u, __ATOMIC_RELAXED, __HIP_MEMORY_SCOPE_AGENT);
        }
        // waves 4-7 proceed to next spin; they cannot overwrite a_s until the
        // whole group (incl. this block's finalize waves) has released t+1.
    }

    // block-reduce reg partial
    for (int off = 32; off; off >>= 1) racc += __shfl_down(racc, off);
    if ((tid & 63) == 0) red_s[tid >> 6] = racc;
    __syncthreads();
    if (tid == 0) {
        float s = 0.0f;
        for (int i = 0; i < NTHREADS / 64; ++i) s += red_s[i];
        partials[bid] = s;
    }
}

// outputs[b][t][:] = hidden[t+1][b][:] @ W_out   (one wave per (b,t))
__global__ __launch_bounds__(256)
void rnn_out(const float* __restrict__ hidden,
             const float* __restrict__ W_out,
             float* __restrict__ outputs)
{
    __shared__ float wout_s[HH * OO];
    const int tid = threadIdx.x;
    for (int i = tid; i < HH * OO; i += 256) wout_s[i] = W_out[i];
    __syncthreads();

    const int gid  = blockIdx.x * 4 + (tid >> 6);   // 0..65535
    const int lane = tid & 63;
    const int b = gid >> 9;
    const int t = gid & (TT - 1);
    const float* hp = hidden + (size_t)(t + 1) * BB * HH + (size_t)b * HH;

    float o0 = 0.0f, o1 = 0.0f, o2 = 0.0f;
#pragma unroll
    for (int q = 0; q < 8; ++q) {
        int k = lane + 64 * q;
        float hv = hp[k];
        o0 = fmaf(hv, wout_s[k * 3 + 0], o0);
        o1 = fmaf(hv, wout_s[k * 3 + 1], o1);
        o2 = fmaf(hv, wout_s[k * 3 + 2], o2);
    }
    for (int off = 32; off; off >>= 1) {
        o0 += __shfl_down(o0, off);
        o1 += __shfl_down(o1, off);
        o2 += __shfl_down(o2, off);
    }
    if (lane == 0) {
        float* op = outputs + (size_t)(b * TT + t) * OO;
        op[0] = o0; op[1] = o1; op[2] = o2;
    }
}

__global__ __launch_bounds__(256)
void rnn_tcr(const float* __restrict__ partials, float* __restrict__ tcr)
{
    __shared__ float red[4];
    const int tid = threadIdx.x;
    float v = partials[tid];   // NBLOCKS == 256 == blockDim
    for (int off = 32; off; off >>= 1) v += __shfl_down(v, off);
    if ((tid & 63) == 0) red[tid >> 6] = v;
    __syncthreads();
    if (tid == 0) {
        float s = red[0] + red[1] + red[2] + red[3];
        *tcr = s * (1.0f / ((float)TT * (float)BB * (float)NREG_));
    }
}

extern "C" void kernel_launch(void* const* d_in, const int* in_sizes, int n_in,
                              void* d_out, int out_size, void* d_ws, size_t ws_size,
                              hipStream_t stream)
{
    (void)in_sizes; (void)n_in; (void)out_size; (void)ws_size;

    const float* x     = (const float*)d_in[0];
    const float* h0    = (const float*)d_in[1];
    const float* W_rec = (const float*)d_in[2];
    const float* W_in  = (const float*)d_in[3];
    const float* W_out = (const float*)d_in[4];
    const float* brec  = (const float*)d_in[5];
    const float* bin   = (const float*)d_in[6];

    float* out     = (float*)d_out;
    float* outputs = out;                                   // (B,T,O)
    float* hidden  = out + (size_t)BB * TT * OO;            // (T+1,B,H)
    float* tcr     = out + (size_t)BB * TT * OO + (size_t)(TT + 1) * BB * HH;

    unsigned int* flags = (unsigned int*)d_ws;
    float* partials = (float*)((char*)d_ws + (size_t)NGROUPS * FLAG_STRIDE * 4);

    // zero the group counters every call (graph replays reuse d_ws)
    (void)hipMemsetAsync(d_ws, 0, (size_t)NGROUPS * FLAG_STRIDE * 4, stream);

    void* args[] = { (void*)&x, (void*)&h0, (void*)&W_rec, (void*)&W_in,
                     (void*)&brec, (void*)&bin, (void*)&hidden,
                     (void*)&flags, (void*)&partials };
    (void)hipLaunchCooperativeKernel((const void*)rnn_main,
                                     dim3(NBLOCKS), dim3(NTHREADS),
                                     args, 0, stream);

    rnn_out<<<dim3((BB * TT) / 4), dim3(256), 0, stream>>>(hidden, W_out, outputs);
    rnn_tcr<<<dim3(1), dim3(256), 0, stream>>>(partials, tcr);
}

// Round 3
// 1212.051 us; speedup vs baseline: 4.7476x; 1.6440x over previous
//
#include <hip/hip_runtime.h>
#include <math.h>

// leaky_current_RNN: B=128, T=512, I=4, H=512, O=3, alpha=0.5, n_reg=256.
// R3: (1) W_rec slice in NAMED float4 registers (macro-generated, no arrays,
// no SROA dependence); (2) matvec via v_readlane broadcast from wave-local
// activation regs -- zero LDS reads in the hot loop; (3) flagless sync:
// producers publish (tanh(h_new), tag) as one 8B relaxed agent atomic into a
// 2-slot exchange buffer; consumer waves poll their own data words directly.

#define BB 128
#define TT 512
#define II 4
#define HH 512
#define OO 3
#define NREG_ 256

#define NTHREADS 512
#define MEMBERS 4
#define ROWS 2
#define NGROUPS 64
#define NBLOCKS (NGROUPS * MEMBERS)

typedef unsigned long long u64;
typedef unsigned int u32;

__device__ __forceinline__ u64 aload(const u64* p) {
    return __hip_atomic_load(p, __ATOMIC_RELAXED, __HIP_MEMORY_SCOPE_AGENT);
}
__device__ __forceinline__ void astore(u64* p, u64 v) {
    __hip_atomic_store(p, v, __ATOMIC_RELAXED, __HIP_MEMORY_SCOPE_AGENT);
}
__device__ __forceinline__ float rlane(float v, int l) {
    return __uint_as_float(__builtin_amdgcn_readlane(__float_as_uint(v), l));
}

#define R16(M) M(0) M(1) M(2) M(3) M(4) M(5) M(6) M(7) \
               M(8) M(9) M(10) M(11) M(12) M(13) M(14) M(15)

// W slice load: wa = cols [memb*128+lane], wb = cols [memb*128+64+lane]
#define WLD(Q) \
    float4 wa##Q, wb##Q; \
    wa##Q.x = Wp[(size_t)(4*Q+0)*HH];      wa##Q.y = Wp[(size_t)(4*Q+1)*HH]; \
    wa##Q.z = Wp[(size_t)(4*Q+2)*HH];      wa##Q.w = Wp[(size_t)(4*Q+3)*HH]; \
    wb##Q.x = Wp[(size_t)(4*Q+0)*HH + 64]; wb##Q.y = Wp[(size_t)(4*Q+1)*HH + 64]; \
    wb##Q.z = Wp[(size_t)(4*Q+2)*HH + 64]; wb##Q.w = Wp[(size_t)(4*Q+3)*HH + 64];

#define MV(Q) \
    { float s0 = rlane(ar0, 4*Q+0), s1 = rlane(ar1, 4*Q+0); \
      acc00 = fmaf(s0, wa##Q.x, acc00); acc01 = fmaf(s0, wb##Q.x, acc01); \
      acc10 = fmaf(s1, wa##Q.x, acc10); acc11 = fmaf(s1, wb##Q.x, acc11); } \
    { float s0 = rlane(ar0, 4*Q+1), s1 = rlane(ar1, 4*Q+1); \
      acc00 = fmaf(s0, wa##Q.y, acc00); acc01 = fmaf(s0, wb##Q.y, acc01); \
      acc10 = fmaf(s1, wa##Q.y, acc10); acc11 = fmaf(s1, wb##Q.y, acc11); } \
    { float s0 = rlane(ar0, 4*Q+2), s1 = rlane(ar1, 4*Q+2); \
      acc00 = fmaf(s0, wa##Q.z, acc00); acc01 = fmaf(s0, wb##Q.z, acc01); \
      acc10 = fmaf(s1, wa##Q.z, acc10); acc11 = fmaf(s1, wb##Q.z, acc11); } \
    { float s0 = rlane(ar0, 4*Q+3), s1 = rlane(ar1, 4*Q+3); \
      acc00 = fmaf(s0, wa##Q.w, acc00); acc01 = fmaf(s0, wb##Q.w, acc01); \
      acc10 = fmaf(s1, wa##Q.w, acc10); acc11 = fmaf(s1, wb##Q.w, acc11); }

__global__ __launch_bounds__(NTHREADS, 2)
void rnn_main(const float* __restrict__ x,
              const float* __restrict__ h0,
              const float* __restrict__ W_rec,
              const float* __restrict__ W_in,
              const float* __restrict__ bias_rec,
              const float* __restrict__ bias_in,
              float* __restrict__ hidden,      // (T+1, B, H) region of d_out
              u64* __restrict__ abuf,          // [2][B][H] (tanh(h), tag)
              float* __restrict__ partials)
{
    const int tid  = threadIdx.x;
    const int bid  = blockIdx.x;
    const int xcd  = bid & 7;
    const int onx  = bid >> 3;
    const int memb = onx & (MEMBERS - 1);
    const int group = xcd * 8 + (onx >> 2);   // 0..63
    const int r0   = group * ROWS;
    const int wid  = tid >> 6;                // k-chunk owner: k in [64*wid, 64*wid+64)
    const int lane = tid & 63;

    __shared__ float sc_s[ROWS][128][9];      // split-k partials (pad 9)
    __shared__ float xbuf[ROWS * TT * II];
    __shared__ float win_s[II][128];
    __shared__ float ub_s[128];
    __shared__ float red_s[NTHREADS / 64];

    // ---- one-time staging ----
    for (int idx = tid; idx < ROWS * TT * II; idx += NTHREADS) {
        int r = idx >> 11, rem = idx & (TT * II - 1);
        xbuf[idx] = x[(size_t)(r0 + r) * (TT * II) + rem];
    }
    if (tid < II * 128) {
        int i = tid >> 7, jj = tid & 127;
        win_s[i][jj] = W_in[i * HH + memb * 128 + jj];
    }
    if (tid < 128) {
        ub_s[tid] = bias_rec[memb * 128 + tid] + bias_in[memb * 128 + tid];
    }

    // ---- W_rec slice into NAMED registers ----
    const float* Wp = W_rec + (size_t)(wid * 64) * HH + memb * 128 + lane;
    R16(WLD)

    // ---- finalize-thread state + initial production (tag 1 = tanh(h0)) ----
    const int fr  = tid >> 7;           // valid when tid < 256
    const int fj  = tid & 127;
    const int fjg = memb * 128 + fj;
    float hprev = 0.0f, zprev = 0.0f, racc = 0.0f;
    if (tid < ROWS * 128) {
        hprev = h0[(size_t)(r0 + fr) * HH + fjg];
        float a0v = tanhf(hprev);
        u64 pv = (u64)__float_as_uint(a0v) | ((u64)1u << 32);
        astore(&abuf[((size_t)(0 * BB + r0 + fr)) * HH + fjg], pv);
        hidden[(size_t)(r0 + fr) * HH + fjg] = hprev;   // hidden[0] = h0
    }

#pragma unroll 1
    for (int t = 0; t < TT; ++t) {
        const int  slot = t & 1;
        const u32  tagc = (u32)(t + 1);
        const u32  tagp = (u32)(t + 2);

        // ---- poll own activation window (the poll IS the data load) ----
        const u64* p0 = abuf + ((size_t)(slot * BB + r0)) * HH + wid * 64 + lane;
        const u64* p1 = p0 + HH;
        u64 u0, u1;
        for (;;) {
            u0 = aload(p0);
            u1 = aload(p1);
            bool ok = ((u32)(u0 >> 32) == tagc) & ((u32)(u1 >> 32) == tagc);
            if (__all(ok)) break;
        }
        float ar0 = __uint_as_float((u32)u0);   // a[row0][64*wid + lane]
        float ar1 = __uint_as_float((u32)u1);   // a[row1][64*wid + lane]

        // ---- matvec: readlane broadcast x register weights ----
        float acc00 = 0.0f, acc01 = 0.0f, acc10 = 0.0f, acc11 = 0.0f;
        R16(MV)

        sc_s[0][lane][wid]      = acc00;
        sc_s[0][lane + 64][wid] = acc01;
        sc_s[1][lane][wid]      = acc10;
        sc_s[1][lane + 64][wid] = acc11;
        __syncthreads();

        // ---- finalize (waves 0-3): reduce, z, h_new, publish ----
        if (tid < ROWS * 128) {
            float q0 = sc_s[fr][fj][0], q1 = sc_s[fr][fj][1];
            float q2 = sc_s[fr][fj][2], q3 = sc_s[fr][fj][3];
            float q4 = sc_s[fr][fj][4], q5 = sc_s[fr][fj][5];
            float q6 = sc_s[fr][fj][6], q7 = sc_s[fr][fj][7];
            float z = ((q0 + q1) + (q2 + q3)) + ((q4 + q5) + (q6 + q7));
            z += ub_s[fj];
            const float* xr = &xbuf[fr * (TT * II) + t * II];
            z = fmaf(xr[0], win_s[0][fj], z);
            z = fmaf(xr[1], win_s[1][fj], z);
            z = fmaf(xr[2], win_s[2][fj], z);
            z = fmaf(xr[3], win_s[3][fj], z);
            float hn = 0.5f * hprev + 0.5f * z;
            float av = tanhf(hn);
            u64 pv = (u64)__float_as_uint(av) | ((u64)tagp << 32);
            astore(&abuf[((size_t)(((t + 1) & 1) * BB + r0 + fr)) * HH + fjg], pv);
            hidden[(size_t)(t + 1) * BB * HH + (size_t)(r0 + fr) * HH + fjg] = hn;
            if (fjg < NREG_) {
                float d1 = hn - hprev;
                racc = fmaf(d1, d1, racc);
                if (t > 0) { float d2 = z - zprev; racc = fmaf(d2, d2, racc); }
                zprev = z;
            }
            hprev = hn;
        }
        __syncthreads();   // protect sc_s for next step
    }

    // ---- block-reduce reg partial ----
    for (int off = 32; off; off >>= 1) racc += __shfl_down(racc, off);
    if ((tid & 63) == 0) red_s[tid >> 6] = racc;
    __syncthreads();
    if (tid == 0) {
        float s = 0.0f;
        for (int i = 0; i < NTHREADS / 64; ++i) s += red_s[i];
        partials[bid] = s;
    }
}

// outputs[b][t][:] = hidden[t+1][b][:] @ W_out   (one wave per (b,t))
__global__ __launch_bounds__(256)
void rnn_out(const float* __restrict__ hidden,
             const float* __restrict__ W_out,
             float* __restrict__ outputs)
{
    __shared__ float wout_s[HH * OO];
    const int tid = threadIdx.x;
    for (int i = tid; i < HH * OO; i += 256) wout_s[i] = W_out[i];
    __syncthreads();

    const int gid  = blockIdx.x * 4 + (tid >> 6);
    const int lane = tid & 63;
    const int b = gid >> 9;
    const int t = gid & (TT - 1);
    const float* hp = hidden + (size_t)(t + 1) * BB * HH + (size_t)b * HH;

    float o0 = 0.0f, o1 = 0.0f, o2 = 0.0f;
#pragma unroll
    for (int q = 0; q < 8; ++q) {
        int k = lane + 64 * q;
        float hv = hp[k];
        o0 = fmaf(hv, wout_s[k * 3 + 0], o0);
        o1 = fmaf(hv, wout_s[k * 3 + 1], o1);
        o2 = fmaf(hv, wout_s[k * 3 + 2], o2);
    }
    for (int off = 32; off; off >>= 1) {
        o0 += __shfl_down(o0, off);
        o1 += __shfl_down(o1, off);
        o2 += __shfl_down(o2, off);
    }
    if (lane == 0) {
        float* op = outputs + (size_t)(b * TT + t) * OO;
        op[0] = o0; op[1] = o1; op[2] = o2;
    }
}

__global__ __launch_bounds__(256)
void rnn_tcr(const float* __restrict__ partials, float* __restrict__ tcr)
{
    __shared__ float red[4];
    const int tid = threadIdx.x;
    float v = partials[tid];   // NBLOCKS == 256 == blockDim
    for (int off = 32; off; off >>= 1) v += __shfl_down(v, off);
    if ((tid & 63) == 0) red[tid >> 6] = v;
    __syncthreads();
    if (tid == 0) {
        float s = red[0] + red[1] + red[2] + red[3];
        *tcr = s * (1.0f / ((float)TT * (float)BB * (float)NREG_));
    }
}

extern "C" void kernel_launch(void* const* d_in, const int* in_sizes, int n_in,
                              void* d_out, int out_size, void* d_ws, size_t ws_size,
                              hipStream_t stream)
{
    (void)in_sizes; (void)n_in; (void)out_size; (void)ws_size;

    const float* x     = (const float*)d_in[0];
    const float* h0    = (const float*)d_in[1];
    const float* W_rec = (const float*)d_in[2];
    const float* W_in  = (const float*)d_in[3];
    const float* W_out = (const float*)d_in[4];
    const float* brec  = (const float*)d_in[5];
    const float* bin   = (const float*)d_in[6];

    float* out     = (float*)d_out;
    float* outputs = out;                                   // (B,T,O)
    float* hidden  = out + (size_t)BB * TT * OO;            // (T+1,B,H)
    float* tcr     = out + (size_t)BB * TT * OO + (size_t)(TT + 1) * BB * HH;

    u64* abuf = (u64*)d_ws;                                 // 2*B*H u64 = 1 MB
    const size_t abuf_bytes = (size_t)2 * BB * HH * sizeof(u64);
    float* partials = (float*)((char*)d_ws + abuf_bytes);

    // zero exchange-buffer tags every call (graph replays reuse d_ws)
    (void)hipMemsetAsync(d_ws, 0, abuf_bytes, stream);

    void* args[] = { (void*)&x, (void*)&h0, (void*)&W_rec, (void*)&W_in,
                     (void*)&brec, (void*)&bin, (void*)&hidden,
                     (void*)&abuf, (void*)&partials };
    (void)hipLaunchCooperativeKernel((const void*)rnn_main,
                                     dim3(NBLOCKS), dim3(NTHREADS),
                                     args, 0, stream);

    rnn_out<<<dim3((BB * TT) / 4), dim3(256), 0, stream>>>(hidden, W_out, outputs);
    rnn_tcr<<<dim3(1), dim3(256), 0, stream>>>(partials, tcr);
}